// Round 6
// baseline (3060.455 us; speedup 1.0000x reference)
//
#include <hip/hip_runtime.h>
#include <stdint.h>

#define B_  256
#define T_  512
#define I_  256
#define H_  512
#define G3_ 1536

typedef _Float16 half8  __attribute__((ext_vector_type(8)));
typedef __fp16   fp16x2 __attribute__((ext_vector_type(2)));   // cvt_pkrtz result type
typedef float    float4v __attribute__((ext_vector_type(4)));

__device__ __forceinline__ float sigmoid_f(float x) { return 1.f / (1.f + __expf(-x)); }
__device__ __forceinline__ float tanh_f(float x) {
  x = fminf(15.f, fmaxf(-15.f, x));
  float e = __expf(2.f * x);
  return (e - 1.f) / (e + 1.f);
}

__device__ __forceinline__ unsigned pk2(float lo, float hi) {
  fp16x2 p = __builtin_amdgcn_cvt_pkrtz(lo, hi);
  return *(unsigned*)&p;
}

__device__ __forceinline__ uint32_t min8_u64x4(const uint64_t f[4]) {
  uint32_t m = 0xFFFFFFFFu;
  #pragma unroll
  for (int k = 0; k < 4; ++k) {
    uint32_t lo = (uint32_t)f[k], hi = (uint32_t)(f[k] >> 32);
    m = m < lo ? m : lo;
    m = m < hi ? m : hi;
  }
  return m;
}

// ---------------------------------------------------------------------------
// Kernel A: igates = (fp16)(x @ w_ih^T + b), 128x128 tile (round-5 version —
// it improved the non-scan time ~190 us; unchanged to isolate the scan change).
// ---------------------------------------------------------------------------
__global__ __launch_bounds__(256) void igates_gemm(
    const float* __restrict__ x, const float* __restrict__ w_ih,
    const float* __restrict__ bias, _Float16* __restrict__ ig)
{
  __shared__ _Float16 Ash[128][72];
  __shared__ _Float16 Bsh[128][72];
  const int tid  = threadIdx.x;
  const int lane = tid & 63;
  const int wv   = tid >> 6;
  const int wm   = wv >> 1, wn = wv & 1;     // wave -> 64x64 quadrant
  const int n0   = blockIdx.x * 128;
  const int m0   = blockIdx.y * 128;         // m = t*256 + b
  const int cn   = lane & 15;
  const int rq   = lane >> 4;

  float4v acc[4][4];
  #pragma unroll
  for (int a = 0; a < 4; ++a)
    #pragma unroll
    for (int c = 0; c < 4; ++c) acc[a][c] = (float4v){0.f, 0.f, 0.f, 0.f};

  for (int kc = 0; kc < I_; kc += 64) {
    #pragma unroll
    for (int i = 0; i < 8; ++i) {
      int e   = tid + (i << 8);
      int row = e >> 4;
      int c4  = e & 15;
      int m   = m0 + row;
      int tt  = m >> 8, bb = m & 255;
      float4 va = *(const float4*)(x + ((size_t)bb * T_ + tt) * I_ + kc + (c4 << 2));
      uint2 ua; ua.x = pk2(va.x, va.y); ua.y = pk2(va.z, va.w);
      *(uint2*)&Ash[row][c4 << 2] = ua;
      float4 vb = *(const float4*)(w_ih + (size_t)(n0 + row) * I_ + kc + (c4 << 2));
      uint2 ub; ub.x = pk2(vb.x, vb.y); ub.y = pk2(vb.z, vb.w);
      *(uint2*)&Bsh[row][c4 << 2] = ub;
    }
    __syncthreads();
    #pragma unroll
    for (int ks = 0; ks < 2; ++ks) {
      int kk = (ks << 5) + (rq << 3);
      half8 af[4], bf[4];
      #pragma unroll
      for (int mt = 0; mt < 4; ++mt)
        af[mt] = *(const half8*)&Ash[(wm << 6) + (mt << 4) + cn][kk];
      #pragma unroll
      for (int nt = 0; nt < 4; ++nt)
        bf[nt] = *(const half8*)&Bsh[(wn << 6) + (nt << 4) + cn][kk];
      #pragma unroll
      for (int mt = 0; mt < 4; ++mt)
        #pragma unroll
        for (int nt = 0; nt < 4; ++nt)
          acc[mt][nt] = __builtin_amdgcn_mfma_f32_16x16x32_f16(af[mt], bf[nt], acc[mt][nt], 0, 0, 0);
    }
    __syncthreads();
  }
  float bv[4];
  #pragma unroll
  for (int nt = 0; nt < 4; ++nt) bv[nt] = bias[n0 + (wn << 6) + (nt << 4) + cn];
  #pragma unroll
  for (int mt = 0; mt < 4; ++mt)
    #pragma unroll
    for (int nt = 0; nt < 4; ++nt) {
      int mrow = m0 + (wm << 6) + (mt << 4) + (rq << 2);
      int ncol = n0 + (wn << 6) + (nt << 4) + cn;
      #pragma unroll
      for (int r = 0; r < 4; ++r)
        ig[(size_t)(mrow + r) * G3_ + ncol] = (_Float16)(acc[mt][nt][r] + bv[nt]);
    }
}

// ---------------------------------------------------------------------------
// Kernel B: persistent GRU scan, v5 — chain multiplexing (2 chains / WG).
//
// Round-5 lesson: per-step sync latency (~2500+ cyc of fabric round trips +
// peer jitter) is near-irreducible; tag-in-data made it worse. So HIDE it:
// each WG serves 2 independent batch-chains sharing the same col-slice (and
// therefore the SAME weight registers). While chain A's h/flag propagates
// through the fabric, the WG computes chain B. Every sync edge gets ~1 slot
// (~1200 cyc) of slack.
//
// 64 WGs = 8 chain-pairs x 8 col-slices. Chain c (0..15) owns batches
// [16c,16c+16); slice gs owns h-cols [64gs, 64gs+64). Slot = (chain, step):
//   1. await own-chain flags >= r (values prefetched one slot ago; spin rare)
//   2. issue h(r) loads (data-dep on spin result — no hoist past the spin)
//   3. s_waitcnt(0): h arrived; ALSO drains prev slot's publish stores
//      (vmcnt is in-order) -> 4. store OTHER chain's flag with no ack stall
//   5. stage h->LDS, 6. MFMA + gate epilogue, 7. publish h(r+1) (u16, no wait)
//   8. prefetch next slot's flags  9. prefetch next slot's ig
// Flag semantics (= v2, proven): flag[c]=v  <=>  this WG published h_c(v) AND
// finished reading h_c(v-1) => peers may overwrite buf[(v+1)&1]. All h/flag
// traffic is relaxed agent-scope (write-through at coherence point, no
// cache-maintenance ops). Placement-independent correctness.
// ---------------------------------------------------------------------------
__global__ __launch_bounds__(256, 1) void gru_scan(
    const _Float16* __restrict__ ig, const float* __restrict__ w_hh,
    const float* __restrict__ b_n,
    _Float16* __restrict__ hb0, _Float16* __restrict__ hb1,
    int* flags)
{
  __shared__ _Float16 h_lds[16][520];   // one chain's h(t): 16 x 512 (+8 pad)
  __shared__ _Float16 hn_lds[16][72];   // h(t+1) slice repack for u64 publish

  const int tid  = threadIdx.x;
  const int lane = tid & 63;
  const int wv   = tid >> 6;                 // wave 0..3
  const int blk  = blockIdx.x;               // 0..63
  const int q    = blk & 7;                  // chain pair; peers share blk&7
  const int gs   = blk >> 3;                 // col-slice 0..7
  const int j0   = gs << 6;
  const int jw   = j0 + (wv << 4);           // first h-col of this wave
  const int cn   = lane & 15;
  const int rq   = lane >> 4;                // 0..3
  const int chain0 = q << 1;

  // --- one-time w_hh fragment load (shared by BOTH chains — key economy) ---
  // B-frag: lane holds W[jw+cn][k], k = ks*32 + rq*8 + i
  half8 wfrag[3][16];
  #pragma unroll
  for (int g = 0; g < 3; ++g) {
    const float* wrow = w_hh + (size_t)(g * H_ + jw + cn) * H_;
    #pragma unroll
    for (int ks = 0; ks < 16; ++ks) {
      int k = (ks << 5) + (rq << 3);
      half8 w;
      #pragma unroll
      for (int i = 0; i < 8; ++i) w[i] = (_Float16)wrow[k + i];
      wfrag[g][ks] = w;
    }
  }
  const float bnv = b_n[jw + cn];

  _Float16* bufs[2] = { hb0, hb1 };

  uint64_t fpre[2][4];     // prefetched flag views per chain parity
  float igv[2][3][4];      // prefetched igates per chain parity

  // bootstrap: ig for slot 0 (chain0, t=0); r=0 needs no flags
  {
    const _Float16* igb = ig + (size_t)((chain0 << 4) + (rq << 2)) * G3_ + jw + cn;
    #pragma unroll
    for (int g = 0; g < 3; ++g)
      #pragma unroll
      for (int r4 = 0; r4 < 4; ++r4)
        igv[0][g][r4] = (float)igb[(size_t)r4 * G3_ + g * H_];
  }

  for (int r = 0; r < T_; ++r) {
    #pragma unroll
    for (int s = 0; s < 2; ++s) {
      const int chain = chain0 | s;
      const int b0    = chain << 4;

      // ---- 1. await: all 8 slice-flags of my chain >= r
      uint32_t mn = 0;
      if (r > 0) {
        mn = min8_u64x4(fpre[s]);
        if (mn < (uint32_t)r) {
          const uint64_t* fp = (const uint64_t*)(flags + (chain << 3));
          uint64_t f[4];
          do {
            #pragma unroll
            for (int k = 0; k < 4; ++k)
              f[k] = __hip_atomic_load(fp + k, __ATOMIC_RELAXED,
                                       __HIP_MEMORY_SCOPE_AGENT);
            mn = min8_u64x4(f);
          } while (mn < (uint32_t)r);
        }
      }

      // ---- 2. h(r) loads (mn>>31 == 0: data dependency pins loads after spin)
      const uint64_t* src = (const uint64_t*)bufs[r & 1]
                          + ((size_t)b0 << 7) + (mn >> 31);
      uint64_t hv[8];
      #pragma unroll
      for (int i = 0; i < 8; ++i)
        hv[i] = __hip_atomic_load(src + (i << 8) + tid,
                                  __ATOMIC_RELAXED, __HIP_MEMORY_SCOPE_AGENT);

      // ---- 3. drain: h arrived; prior publish stores acked (in-order vmcnt)
      __builtin_amdgcn_s_waitcnt(0);

      // ---- 4. other chain's flag (its publish was last slot, now drained)
      {
        int fv = (s == 0) ? r : (r + 1);
        if (!(s == 0 && r == 0) && tid == 0)
          __hip_atomic_store(&flags[((chain ^ 1) << 3) | gs], fv,
                             __ATOMIC_RELAXED, __HIP_MEMORY_SCOPE_AGENT);
      }

      // ---- 5. stage h -> LDS
      #pragma unroll
      for (int i = 0; i < 8; ++i) {
        int idx = (i << 8) + tid;
        int row = idx >> 7, c = idx & 127;
        *(uint64_t*)&h_lds[row][c << 2] = hv[i];
      }
      __syncthreads();

      // ---- 6. MFMA: 3 gates x 16 K-chunks (even/odd acc split) + epilogue
      float4v acc[3][2];
      #pragma unroll
      for (int g = 0; g < 3; ++g) {
        acc[g][0] = (float4v){0.f, 0.f, 0.f, 0.f};
        acc[g][1] = (float4v){0.f, 0.f, 0.f, 0.f};
      }
      #pragma unroll
      for (int ks = 0; ks < 16; ++ks) {
        half8 a = *(const half8*)&h_lds[cn][(ks << 5) + (rq << 3)];
        int pp = ks & 1;
        acc[0][pp] = __builtin_amdgcn_mfma_f32_16x16x32_f16(a, wfrag[0][ks], acc[0][pp], 0, 0, 0);
        acc[1][pp] = __builtin_amdgcn_mfma_f32_16x16x32_f16(a, wfrag[1][ks], acc[1][pp], 0, 0, 0);
        acc[2][pp] = __builtin_amdgcn_mfma_f32_16x16x32_f16(a, wfrag[2][ks], acc[2][pp], 0, 0, 0);
      }
      #pragma unroll
      for (int r4 = 0; r4 < 4; ++r4) {
        float rg = sigmoid_f(igv[s][0][r4] + acc[0][0][r4] + acc[0][1][r4]);
        float zg = sigmoid_f(igv[s][1][r4] + acc[1][0][r4] + acc[1][1][r4]);
        float nv = tanh_f(igv[s][2][r4] + rg * (acc[2][0][r4] + acc[2][1][r4] + bnv));
        float hp = (float)h_lds[(rq << 2) + r4][jw + cn];
        hn_lds[(rq << 2) + r4][(wv << 4) + cn] = (_Float16)(nv + zg * (hp - nv));
      }
      __syncthreads();

      // ---- 7. publish h(r+1) slice: 256 u64 write-through stores, NO wait
      {
        int row = tid >> 4, c = tid & 15;
        uint64_t v = *(const uint64_t*)&hn_lds[row][c << 2];
        __hip_atomic_store((uint64_t*)bufs[(r + 1) & 1]
                               + ((size_t)(b0 + row) << 7) + (gs << 4) + c,
                           v, __ATOMIC_RELAXED, __HIP_MEMORY_SCOPE_AGENT);
      }

      // ---- 8. prefetch next slot's flags (chain^1)
      {
        const uint64_t* fpn = (const uint64_t*)(flags + ((chain ^ 1) << 3));
        #pragma unroll
        for (int k = 0; k < 4; ++k)
          fpre[s ^ 1][k] = __hip_atomic_load(fpn + k, __ATOMIC_RELAXED,
                                             __HIP_MEMORY_SCOPE_AGENT);
      }
      // ---- 9. prefetch next slot's ig (chain^1, step tn)
      {
        int tn = (s == 0) ? r : (r + 1 < T_ ? r + 1 : T_ - 1);
        const _Float16* igb = ig
            + (size_t)(tn * B_ + ((chain ^ 1) << 4) + (rq << 2)) * G3_ + jw + cn;
        #pragma unroll
        for (int g = 0; g < 3; ++g)
          #pragma unroll
          for (int r4 = 0; r4 < 4; ++r4)
            igv[s ^ 1][g][r4] = (float)igb[(size_t)r4 * G3_ + g * H_];
      }
    }
  }
}

// ---------------------------------------------------------------------------
// Kernel C: e[b] = h_T[b] . w_proj + b_proj   (h_T in hb0, T even)
// ---------------------------------------------------------------------------
__global__ __launch_bounds__(64) void proj_kernel(
    const _Float16* __restrict__ h, const float* __restrict__ w_proj,
    const float* __restrict__ b_proj, float* __restrict__ out)
{
  int b = blockIdx.x;
  int lane = threadIdx.x;
  float s = 0.f;
  #pragma unroll
  for (int i = 0; i < 8; ++i) {
    int j = lane + (i << 6);
    s += (float)h[((size_t)b << 9) + j] * w_proj[j];
  }
  #pragma unroll
  for (int off = 32; off > 0; off >>= 1) s += __shfl_down(s, off, 64);
  if (lane == 0) out[b] = s + b_proj[0];
}

// ---------------------------------------------------------------------------
extern "C" void kernel_launch(void* const* d_in, const int* in_sizes, int n_in,
                              void* d_out, int out_size, void* d_ws, size_t ws_size,
                              hipStream_t stream) {
  const float* x      = (const float*)d_in[0];
  const float* w_ih   = (const float*)d_in[1];
  const float* w_hh   = (const float*)d_in[2];
  const float* bias   = (const float*)d_in[3];
  const float* b_n    = (const float*)d_in[4];
  const float* w_proj = (const float*)d_in[5];
  const float* b_proj = (const float*)d_in[6];
  float* out = (float*)d_out;

  char* ws = (char*)d_ws;
  const size_t IG_BYTES = (size_t)T_ * B_ * G3_ * sizeof(_Float16); // 402,653,184
  const size_t HB_BYTES = (size_t)B_ * H_ * sizeof(_Float16);       // 262,144
  _Float16* igbuf = (_Float16*)ws;
  _Float16* hbuf0 = (_Float16*)(ws + IG_BYTES);
  _Float16* hbuf1 = (_Float16*)(ws + IG_BYTES + HB_BYTES);
  int*      flags = (int*)(ws + IG_BYTES + 2 * HB_BYTES);

  // zero h(0) buffer, h(1) buffer, flags — capture-safe
  (void)hipMemsetAsync(ws + IG_BYTES, 0, 2 * HB_BYTES + 1024, stream);

  dim3 gridA(G3_ / 128, (T_ * B_) / 128);   // (12, 1024)
  igates_gemm<<<gridA, 256, 0, stream>>>(x, w_ih, bias, igbuf);
  gru_scan<<<64, 256, 0, stream>>>(igbuf, w_hh, b_n, hbuf0, hbuf1, flags);
  proj_kernel<<<B_, 64, 0, stream>>>(hbuf0, w_proj, b_proj, out);
}